// Round 1
// baseline (318.625 us; speedup 1.0000x reference)
//
#include <hip/hip_runtime.h>
#include <cstdint>
#include <cstddef>
#include <type_traits>

typedef float  f32x4    __attribute__((ext_vector_type(4)));
typedef float  f32x16   __attribute__((ext_vector_type(16)));
typedef __bf16 bf16x8   __attribute__((ext_vector_type(8)));
typedef short  short4_t __attribute__((ext_vector_type(4)));
typedef short  short8_t __attribute__((ext_vector_type(8)));
typedef unsigned int uint4_t __attribute__((ext_vector_type(4)));

// hw f32->bf16 (v_cvt_pk_bf16_f32 on gfx950), RNE
__device__ __forceinline__ short f2bf(float f) {
  return __builtin_bit_cast(short, (__bf16)f);
}

__device__ __forceinline__ unsigned pk2bf(float a, float b) {
  unsigned lo = (unsigned short)__builtin_bit_cast(unsigned short, f2bf(a));
  unsigned hi = (unsigned short)__builtin_bit_cast(unsigned short, f2bf(b));
  return lo | (hi << 16);
}

__device__ __forceinline__ void gl_lds16(const void* g, void* l) {
  __builtin_amdgcn_global_load_lds((const __attribute__((address_space(1))) void*)g,
                                   (__attribute__((address_space(3))) void*)l, 16, 0, 0);
}

// ---------------- elementwise fp32 -> bf16 ----------------
__global__ void convert_bf16(const float* __restrict__ X, short* __restrict__ Xb) {
  int i = (blockIdx.x * 256 + threadIdx.x) * 4;
  f32x4 v = *(const f32x4*)&X[i];
  short4_t o;
#pragma unroll
  for (int j = 0; j < 4; j++) o[j] = f2bf(v[j]);
  *(short4_t*)&Xb[i] = o;
}

// ---------------- transpose-convert W[K][N] fp32 -> WT[N][K] bf16 ----------------
__global__ void transpose_bf16(const float* __restrict__ W, short* __restrict__ WT,
                               int K, int N) {
  __shared__ float tile[32][33];
  int tx = threadIdx.x & 31, ty = threadIdx.x >> 5;    // ty 0..7
  int n0 = blockIdx.x * 32, k0 = blockIdx.y * 32;
#pragma unroll
  for (int i = 0; i < 32; i += 8)
    tile[ty + i][tx] = W[(size_t)(k0 + ty + i) * N + n0 + tx];
  __syncthreads();
#pragma unroll
  for (int i = 0; i < 32; i += 8)
    WT[(size_t)(n0 + ty + i) * K + k0 + tx] = f2bf(tile[tx][ty + i]);
}

// ---------------- m97-style bf16 GEMM, Bt is [N][K] ----------------
// MODE 0: fp32 out [M][N].
// MODE 1: scatter bf16 into Q [B,H,T,D], K [B,H,T,D], V^T [B,H,D,T].
template <int MODE>
__global__ __launch_bounds__(256, 2) void gemm_bt(
    const short* __restrict__ A, const short* __restrict__ Bt,
    float* __restrict__ outf, short* __restrict__ Qo, short* __restrict__ Ko,
    short* __restrict__ Vo, int M, int N, int K) {
  __shared__ alignas(16) short As[128 * 32];
  __shared__ alignas(16) short Bs[128 * 32];
  const int tid = threadIdx.x;
  const int lane = tid & 63;
  const int g = lane & 15, q = lane >> 4;
  const int wave = tid >> 6;
  const int m0 = blockIdx.y * 128, n0 = blockIdx.x * 128;
  const int wm = (wave >> 1) * 64, wn = (wave & 1) * 64;

  const int srow = tid >> 2;            // 0..63
  const int scol = (tid & 3) * 8;       // element col within BK
  const short* ap0 = A  + (size_t)(m0 + srow) * K + scol;
  const short* ap1 = A  + (size_t)(m0 + 64 + srow) * K + scol;
  const short* bp0 = Bt + (size_t)(n0 + srow) * K + scol;
  const short* bp1 = Bt + (size_t)(n0 + 64 + srow) * K + scol;
  short* la0 = &As[tid * 8];
  short* la1 = &As[(tid + 256) * 8];
  short* lb0 = &Bs[tid * 8];
  short* lb1 = &Bs[(tid + 256) * 8];

  f32x4 acc[4][4] = {};

  for (int k0 = 0; k0 < K; k0 += 32) {
    __syncthreads();
    gl_lds16(ap0 + k0, la0);
    gl_lds16(ap1 + k0, la1);
    gl_lds16(bp0 + k0, lb0);
    gl_lds16(bp1 + k0, lb1);
    __syncthreads();
    bf16x8 af[4], bfr[4];
#pragma unroll
    for (int mt = 0; mt < 4; mt++)
      af[mt] = *(const bf16x8*)&As[(wm + mt * 16 + g) * 32 + q * 8];
#pragma unroll
    for (int nt = 0; nt < 4; nt++)
      bfr[nt] = *(const bf16x8*)&Bs[(wn + nt * 16 + g) * 32 + q * 8];
#pragma unroll
    for (int mt = 0; mt < 4; mt++)
#pragma unroll
      for (int nt = 0; nt < 4; nt++)
        acc[mt][nt] = __builtin_amdgcn_mfma_f32_16x16x32_bf16(af[mt], bfr[nt],
                                                              acc[mt][nt], 0, 0, 0);
  }

  if (MODE == 0) {
#pragma unroll
    for (int mt = 0; mt < 4; mt++)
#pragma unroll
      for (int nt = 0; nt < 4; nt++) {
        int n = n0 + wn + nt * 16 + g;
        int mbase = m0 + wm + mt * 16 + q * 4;
#pragma unroll
        for (int r = 0; r < 4; r++)
          outf[(size_t)(mbase + r) * N + n] = acc[mt][nt][r];
      }
  } else {
#pragma unroll
    for (int nt = 0; nt < 4; nt++) {
      int n = n0 + wn + nt * 16 + g;
      int which = n >> 10;            // 0=q 1=k 2=v
      int c = n & 1023;
      int h = c >> 6, d = c & 63;
#pragma unroll
      for (int mt = 0; mt < 4; mt++) {
        int mbase = m0 + wm + mt * 16 + q * 4;
        int b = mbase >> 11, t = mbase & 2047;   // 4 rows never cross b
        if (which == 2) {
          // V^T: [b,h,d,t] — t consecutive over r -> packed 8B store
          short4_t pv;
#pragma unroll
          for (int r = 0; r < 4; r++) pv[r] = f2bf(acc[mt][nt][r]);
          *(short4_t*)&Vo[((size_t)((b << 4) + h) * 64 + d) * 2048 + t] = pv;
        } else {
          short* dst = (which == 0) ? Qo : Ko;
#pragma unroll
          for (int r = 0; r < 4; r++)
            dst[((size_t)((b << 4) + h) * 2048 + (t + r)) * 64 + d] =
                f2bf(acc[mt][nt][r]);
        }
      }
    }
  }
}

// ---------------- causal flash attention, 32x32 MFMA, zero-LDS ----------------
// Q,K: [B,H,T,D] bf16.  Vt: [B,H,D,T] bf16.  O: [B,T,H*D] bf16.
// Each wave owns a 32-row q-subtile; each lane owns ONE q-row (col = lane&31 of
// the S^T = K*Q^T accumulator). No LDS, no barriers: K/V fragments are loaded
// straight from global (tiles are L2-resident; grid puts all q-blocks of a
// (b,h) on one XCD). Softmax is fully in-register: one shfl_xor(32) per
// reduce; P^T B-fragments are built with v_permlane32_swap_b32.
//
// 32x32x16 layouts (family-consistent with the verified 16x16x32 use above):
//   A: row = lane&31, k = (lane>>5)*8 + j
//   B: col = lane&31, k = (lane>>5)*8 + j
//   C/D: col = lane&31, row = (reg&3) + 8*(reg>>2) + 4*(lane>>5)
// P^T exchange per 16-key window (rb = (kb&1)*8):
//   X = pack(regs rb..rb+3)   -> window-keys 4*qh + 0..3
//   Y = pack(regs rb+4..rb+7) -> window-keys 8 + 4*qh + 0..3
//   v_permlane32_swap_b32 X,Y  (vdst[32:63] <-> vsrc[0:31]) gives per lane qh:
//     X' = keys qh*8 + {0..3}, Y' = keys qh*8 + {4..7}  == B-frag slots j0..7.
__global__ __launch_bounds__(256, 2) void attn_fwd(
    const short* __restrict__ Qg, const short* __restrict__ Kg,
    const short* __restrict__ Vt, short* __restrict__ Og) {
  const int tid = threadIdx.x, lane = tid & 63, wave = tid >> 6;
  const int c = lane & 31;        // q-row within the wave's 32-row subtile
  const int qh = lane >> 5;       // 0/1: k-half of fragments
  const int bh = blockIdx.x;      // bh fastest => all q-blocks of a bh on 1 XCD
  const int b = bh >> 4, h = bh & 15;
  const size_t base = (size_t)bh * (2048 * 64);
  const float cs = 0.18033688011f;     // (1/sqrt(64)) * log2(e)

  const short* Kp = Kg + base + (size_t)c * 64 + qh * 8;    // [t][d] frag base
  const short* Vp = Vt + base + (size_t)c * 2048 + qh * 8;  // [d][t] frag base
  const int q_rel = wave * 32 + c;

  for (int half = 0; half < 2; half++) {
    const int qt = (half == 0) ? (int)blockIdx.y : 15 - (int)blockIdx.y;
    const int qrow = qt * 128 + wave * 32 + c;

    // Q fragments (pre-scaled), one q-row per lane
    bf16x8 bq[4];
#pragma unroll
    for (int ks = 0; ks < 4; ks++) {
      bf16x8 v = *(const bf16x8*)&Qg[base + (size_t)qrow * 64 + ks * 16 + qh * 8];
#pragma unroll
      for (int j = 0; j < 8; j++) v[j] = (__bf16)((float)v[j] * cs);
      bq[ks] = v;
    }

    f32x16 ot[2] = {};                  // O^T acc: d-tiles {0..31},{32..63}
    float m_run = -1e30f, l_run = 0.0f;

    auto step = [&](auto diagc, int kt) {
      constexpr bool DIAG = decltype(diagc)::value;

      // ---- K fragments for this 128-key tile (16 x dwordx4) ----
      bf16x8 af[4][4];
      const short* Kt = Kp + kt * (128 * 64);
#pragma unroll
      for (int mt = 0; mt < 4; mt++)
#pragma unroll
        for (int ks = 0; ks < 4; ks++)
          af[mt][ks] = *(const bf16x8*)&Kt[mt * (32 * 64) + ks * 16];

      // ---- S^T = K * Q^T ----
      f32x16 st[4] = {};
      __builtin_amdgcn_s_setprio(1);
#pragma unroll
      for (int mt = 0; mt < 4; mt++)
#pragma unroll
        for (int ks = 0; ks < 4; ks++)
          st[mt] = __builtin_amdgcn_mfma_f32_32x32x16_bf16(af[mt][ks], bq[ks],
                                                           st[mt], 0, 0, 0);
      __builtin_amdgcn_s_setprio(0);

      // ---- V^T fragments: issue now, latency hides under softmax ----
      bf16x8 va[8][2];
      const short* Vtt = Vp + kt * 128;
#pragma unroll
      for (int kb = 0; kb < 8; kb++)
#pragma unroll
        for (int mt = 0; mt < 2; mt++)
          va[kb][mt] = *(const bf16x8*)&Vtt[mt * (32 * 2048) + kb * 16];

      // ---- softmax (fully in-register; one shfl pair with lane^32) ----
      float tm[4];
#pragma unroll
      for (int mt = 0; mt < 4; mt++) {
        float t = -1e30f;
#pragma unroll
        for (int r = 0; r < 16; r++) {
          if (DIAG) {
            int krel = mt * 32 + (r & 3) + 8 * (r >> 2) + 4 * qh;
            if (krel > q_rel) st[mt][r] = -1e30f;
          }
          t = fmaxf(t, st[mt][r]);
        }
        tm[mt] = t;
      }
      float tmax = fmaxf(fmaxf(tm[0], tm[1]), fmaxf(tm[2], tm[3]));
      tmax = fmaxf(tmax, __shfl_xor(tmax, 32));
      const float mnew = fmaxf(m_run, tmax);
      const float alpha = __builtin_amdgcn_exp2f(m_run - mnew);
      float ps[4];
#pragma unroll
      for (int mt = 0; mt < 4; mt++) {
        float s = 0.0f;
#pragma unroll
        for (int r = 0; r < 16; r++) {
          float p = __builtin_amdgcn_exp2f(st[mt][r] - mnew);
          s += p;
          st[mt][r] = p;
        }
        ps[mt] = s;
      }
      float psum = (ps[0] + ps[1]) + (ps[2] + ps[3]);
      psum += __shfl_xor(psum, 32);
      l_run = l_run * alpha + psum;
      m_run = mnew;
#pragma unroll
      for (int mt = 0; mt < 2; mt++)
#pragma unroll
        for (int r = 0; r < 16; r++) ot[mt][r] *= alpha;

      // ---- O^T += V^T * P^T (P^T built in-register via permlane32_swap) ----
      __builtin_amdgcn_s_setprio(1);
#pragma unroll
      for (int kb = 0; kb < 8; kb++) {
        const int mt = kb >> 1, rb = (kb & 1) * 8;
        unsigned x0 = pk2bf(st[mt][rb + 0], st[mt][rb + 1]);
        unsigned x1 = pk2bf(st[mt][rb + 2], st[mt][rb + 3]);
        unsigned y0 = pk2bf(st[mt][rb + 4], st[mt][rb + 5]);
        unsigned y1 = pk2bf(st[mt][rb + 6], st[mt][rb + 7]);
        asm("v_permlane32_swap_b32 %0, %1" : "+v"(x0), "+v"(y0));
        asm("v_permlane32_swap_b32 %0, %1" : "+v"(x1), "+v"(y1));
        uint4_t pw;
        pw[0] = x0; pw[1] = x1; pw[2] = y0; pw[3] = y1;
        bf16x8 pb = __builtin_bit_cast(bf16x8, pw);
#pragma unroll
        for (int mt2 = 0; mt2 < 2; mt2++)
          ot[mt2] = __builtin_amdgcn_mfma_f32_32x32x16_bf16(va[kb][mt2], pb,
                                                            ot[mt2], 0, 0, 0);
      }
      __builtin_amdgcn_s_setprio(0);
    };

    for (int kt = 0; kt < qt; kt++)
      step(std::integral_constant<bool, false>{}, kt);
    step(std::integral_constant<bool, true>{}, qt);

    // ---- epilogue: O[b, qrow, h*64+d] = O^T / l ----
    const float inv = 1.0f / l_run;
    const size_t obase = ((size_t)b * 2048 + qrow) * 1024 + h * 64 + qh * 4;
#pragma unroll
    for (int mt = 0; mt < 2; mt++)
#pragma unroll
      for (int rr = 0; rr < 4; rr++) {
        short4_t ov;
#pragma unroll
        for (int i = 0; i < 4; i++) ov[i] = f2bf(ot[mt][rr * 4 + i] * inv);
        *(short4_t*)&Og[obase + mt * 32 + rr * 8] = ov;
      }
  }
}

// ---------------- launch ----------------
extern "C" void kernel_launch(void* const* d_in, const int* in_sizes, int n_in,
                              void* d_out, int out_size, void* d_ws, size_t ws_size,
                              hipStream_t stream) {
  const float* x      = (const float*)d_in[0];   // [4,2048,1024]
  const float* w_qkv  = (const float*)d_in[1];   // [1024,3072]
  const float* w_proj = (const float*)d_in[2];   // [1024,1024]
  float* out = (float*)d_out;                    // [4,2048,1024]

  char* ws = (char*)d_ws;
  short* xb     = (short*)(ws);                    // 16 MB bf16 x; reused as O
  short* wqkvT  = (short*)(ws + 16777216);         // 6 MB
  short* wprojT = (short*)(ws + 23068672);         // 2 MB
  short* Qb     = (short*)(ws + 25165824);         // 16 MB  [B,H,T,D]
  short* Kb     = (short*)(ws + 41943040);         // 16 MB  [B,H,T,D]
  short* Vtb    = (short*)(ws + 58720256);         // 16 MB  [B,H,D,T]

  convert_bf16<<<8192, 256, 0, stream>>>(x, xb);
  {
    dim3 gq(96, 32); transpose_bf16<<<gq, 256, 0, stream>>>(w_qkv, wqkvT, 1024, 3072);
    dim3 gp(32, 32); transpose_bf16<<<gp, 256, 0, stream>>>(w_proj, wprojT, 1024, 1024);
  }
  {
    dim3 g(24, 64);  // N/128, M/128
    gemm_bt<1><<<g, 256, 0, stream>>>(xb, wqkvT, nullptr, Qb, Kb, Vtb, 8192, 3072, 1024);
  }
  {
    // grid: x = b*h (same bh -> same XCD under linear%8 round-robin),
    //       y = paired q-tiles (qt, 15-qt) -> uniform 17 k-iterations
    dim3 g(64, 8);
    attn_fwd<<<g, 256, 0, stream>>>(Qb, Kb, Vtb, xb /* O, reusing xb */);
  }
  {
    dim3 g(8, 64);
    gemm_bt<0><<<g, 256, 0, stream>>>(xb, wprojT, out, nullptr, nullptr, nullptr,
                                      8192, 1024, 1024);
  }
}

// Round 2
// 254.250 us; speedup vs baseline: 1.2532x; 1.2532x over previous
//
#include <hip/hip_runtime.h>
#include <cstdint>
#include <cstddef>
#include <type_traits>

typedef float  f32x4    __attribute__((ext_vector_type(4)));
typedef float  f32x16   __attribute__((ext_vector_type(16)));
typedef __bf16 bf16x8   __attribute__((ext_vector_type(8)));
typedef short  short4_t __attribute__((ext_vector_type(4)));
typedef short  short8_t __attribute__((ext_vector_type(8)));
typedef unsigned int uint4_t __attribute__((ext_vector_type(4)));

// hw f32->bf16 (v_cvt_pk_bf16_f32 on gfx950), RNE
__device__ __forceinline__ short f2bf(float f) {
  return __builtin_bit_cast(short, (__bf16)f);
}

__device__ __forceinline__ unsigned pk2bf(float a, float b) {
  unsigned lo = (unsigned short)__builtin_bit_cast(unsigned short, f2bf(a));
  unsigned hi = (unsigned short)__builtin_bit_cast(unsigned short, f2bf(b));
  return lo | (hi << 16);
}

__device__ __forceinline__ void gl_lds16(const void* g, void* l) {
  __builtin_amdgcn_global_load_lds((const __attribute__((address_space(1))) void*)g,
                                   (__attribute__((address_space(3))) void*)l, 16, 0, 0);
}

// ---------------- elementwise fp32 -> bf16 ----------------
__global__ void convert_bf16(const float* __restrict__ X, short* __restrict__ Xb) {
  int i = (blockIdx.x * 256 + threadIdx.x) * 4;
  f32x4 v = *(const f32x4*)&X[i];
  short4_t o;
#pragma unroll
  for (int j = 0; j < 4; j++) o[j] = f2bf(v[j]);
  *(short4_t*)&Xb[i] = o;
}

// ---------------- transpose-convert W[K][N] fp32 -> WT[N][K] bf16 ----------------
__global__ void transpose_bf16(const float* __restrict__ W, short* __restrict__ WT,
                               int K, int N) {
  __shared__ float tile[32][33];
  int tx = threadIdx.x & 31, ty = threadIdx.x >> 5;    // ty 0..7
  int n0 = blockIdx.x * 32, k0 = blockIdx.y * 32;
#pragma unroll
  for (int i = 0; i < 32; i += 8)
    tile[ty + i][tx] = W[(size_t)(k0 + ty + i) * N + n0 + tx];
  __syncthreads();
#pragma unroll
  for (int i = 0; i < 32; i += 8)
    WT[(size_t)(n0 + ty + i) * K + k0 + tx] = f2bf(tile[tx][ty + i]);
}

// ---------------- m97-style bf16 GEMM, Bt is [N][K] ----------------
// MODE 0: fp32 out [M][N].
// MODE 1: scatter bf16 into Q [B,H,T,D], K [B,H,T,D], V^T [B,H,D,T].
template <int MODE>
__global__ __launch_bounds__(256, 2) void gemm_bt(
    const short* __restrict__ A, const short* __restrict__ Bt,
    float* __restrict__ outf, short* __restrict__ Qo, short* __restrict__ Ko,
    short* __restrict__ Vo, int M, int N, int K) {
  __shared__ alignas(16) short As[128 * 32];
  __shared__ alignas(16) short Bs[128 * 32];
  const int tid = threadIdx.x;
  const int lane = tid & 63;
  const int g = lane & 15, q = lane >> 4;
  const int wave = tid >> 6;
  const int m0 = blockIdx.y * 128, n0 = blockIdx.x * 128;
  const int wm = (wave >> 1) * 64, wn = (wave & 1) * 64;

  const int srow = tid >> 2;            // 0..63
  const int scol = (tid & 3) * 8;       // element col within BK
  const short* ap0 = A  + (size_t)(m0 + srow) * K + scol;
  const short* ap1 = A  + (size_t)(m0 + 64 + srow) * K + scol;
  const short* bp0 = Bt + (size_t)(n0 + srow) * K + scol;
  const short* bp1 = Bt + (size_t)(n0 + 64 + srow) * K + scol;
  short* la0 = &As[tid * 8];
  short* la1 = &As[(tid + 256) * 8];
  short* lb0 = &Bs[tid * 8];
  short* lb1 = &Bs[(tid + 256) * 8];

  f32x4 acc[4][4] = {};

  for (int k0 = 0; k0 < K; k0 += 32) {
    __syncthreads();
    gl_lds16(ap0 + k0, la0);
    gl_lds16(ap1 + k0, la1);
    gl_lds16(bp0 + k0, lb0);
    gl_lds16(bp1 + k0, lb1);
    __syncthreads();
    bf16x8 af[4], bfr[4];
#pragma unroll
    for (int mt = 0; mt < 4; mt++)
      af[mt] = *(const bf16x8*)&As[(wm + mt * 16 + g) * 32 + q * 8];
#pragma unroll
    for (int nt = 0; nt < 4; nt++)
      bfr[nt] = *(const bf16x8*)&Bs[(wn + nt * 16 + g) * 32 + q * 8];
#pragma unroll
    for (int mt = 0; mt < 4; mt++)
#pragma unroll
      for (int nt = 0; nt < 4; nt++)
        acc[mt][nt] = __builtin_amdgcn_mfma_f32_16x16x32_bf16(af[mt], bfr[nt],
                                                              acc[mt][nt], 0, 0, 0);
  }

  if (MODE == 0) {
#pragma unroll
    for (int mt = 0; mt < 4; mt++)
#pragma unroll
      for (int nt = 0; nt < 4; nt++) {
        int n = n0 + wn + nt * 16 + g;
        int mbase = m0 + wm + mt * 16 + q * 4;
#pragma unroll
        for (int r = 0; r < 4; r++)
          outf[(size_t)(mbase + r) * N + n] = acc[mt][nt][r];
      }
  } else {
#pragma unroll
    for (int nt = 0; nt < 4; nt++) {
      int n = n0 + wn + nt * 16 + g;
      int which = n >> 10;            // 0=q 1=k 2=v
      int c = n & 1023;
      int h = c >> 6, d = c & 63;
#pragma unroll
      for (int mt = 0; mt < 4; mt++) {
        int mbase = m0 + wm + mt * 16 + q * 4;
        int b = mbase >> 11, t = mbase & 2047;   // 4 rows never cross b
        if (which == 2) {
          // V^T: [b,h,d,t] — t consecutive over r -> packed 8B store
          short4_t pv;
#pragma unroll
          for (int r = 0; r < 4; r++) pv[r] = f2bf(acc[mt][nt][r]);
          *(short4_t*)&Vo[((size_t)((b << 4) + h) * 64 + d) * 2048 + t] = pv;
        } else {
          short* dst = (which == 0) ? Qo : Ko;
#pragma unroll
          for (int r = 0; r < 4; r++)
            dst[((size_t)((b << 4) + h) * 2048 + (t + r)) * 64 + d] =
                f2bf(acc[mt][nt][r]);
        }
      }
    }
  }
}

// ---------------- causal flash attention, 32x32 MFMA ----------------
// Q,K: [B,H,T,D] bf16.  Vt: [B,H,D,T] bf16.  O: [B,T,H*D] bf16.
// Each wave owns a 32-row q-subtile; each lane owns ONE q-row (col = lane&31
// of the S^T = K*Q^T accumulator). Softmax fully in-register (one
// shfl_xor(32) per reduce); P^T B-fragments built with v_permlane32_swap_b32.
//
// K/V tiles are staged in LDS (shared by all 4 waves; 4x fewer global loads
// than per-wave direct), in a BLOCKED layout that matches the fragment reads:
//   K unit (mt,ks,qh,c): idx16 = ((mt*4+ks)*2+qh)*32 + c
//   V unit (kb,mtv,qh,c): idx16 = ((kb*2+mtv)*2+qh)*32 + c
// so every ds_read_b128 is 64 lanes x contiguous 16B = conflict-free, and
// global_load_lds (linear lane order) writes it directly (per-lane global
// source address carries the permutation). Double-buffered, ONE barrier per
// k-tile: loads for tile kt+1 are issued right after the barrier (before
// compute on kt); the next barrier's implicit vmcnt(0) drain is the ready
// signal — the loads have a full compute phase to fly.
//
// 32x32x16 layouts (harness-verified in R1):
//   A: row = lane&31, k = (lane>>5)*8 + j
//   B: col = lane&31, k = (lane>>5)*8 + j
//   C/D: col = lane&31, row = (reg&3) + 8*(reg>>2) + 4*(lane>>5)
__global__ __launch_bounds__(256, 2) void attn_fwd(
    const short* __restrict__ Qg, const short* __restrict__ Kg,
    const short* __restrict__ Vt, short* __restrict__ Og) {
  __shared__ alignas(16) short Ks[2][8192];   // 2 x 16 KB
  __shared__ alignas(16) short Vs[2][8192];   // 2 x 16 KB
  const int tid = threadIdx.x, lane = tid & 63, wave = tid >> 6;
  const int c = lane & 31;        // q-row within the wave's 32-row subtile
  const int qh = lane >> 5;       // 0/1: k-half of fragments
  const int bh = blockIdx.x;      // bh fastest => q-blocks of a bh co-XCD
  const int b = bh >> 4, h = bh & 15;
  const size_t base = (size_t)bh * (2048 * 64);
  const float cs = 0.18033688011f;     // (1/sqrt(64)) * log2(e)
  const int q_rel = wave * 32 + c;
  const int laneoff = (qh * 32 + c) * 8;   // short offset of lane's 16B slot

  // per-thread stage sources (tile-invariant parts precomputed)
  const short* kp[4];
  const short* vp[4];
#pragma unroll
  for (int i = 0; i < 4; i++) {
    int u = i * 256 + tid;
    int uc = u & 31, uq = (u >> 5) & 1;
    kp[i] = Kg + base + (size_t)((u >> 8) * 32 + uc) * 64 + ((u >> 6) & 3) * 16 + uq * 8;
    vp[i] = Vt + base + (size_t)(((u >> 6) & 1) * 32 + uc) * 2048 + (u >> 7) * 16 + uq * 8;
  }

  auto stage = [&](int buf, int kt) {
    short* kd = &Ks[buf][tid * 8];
    short* vd = &Vs[buf][tid * 8];
#pragma unroll
    for (int i = 0; i < 4; i++) {
      gl_lds16(kp[i] + (size_t)kt * (128 * 64), kd + i * 2048);
      gl_lds16(vp[i] + (size_t)kt * 128, vd + i * 2048);
    }
  };

  int cur = 0;

  for (int half = 0; half < 2; half++) {
    const int qt = (half == 0) ? (int)blockIdx.y : 15 - (int)blockIdx.y;
    const int qrow = qt * 128 + wave * 32 + c;

    // Q fragments (pre-scaled), one q-row per lane
    bf16x8 bq[4];
#pragma unroll
    for (int ks = 0; ks < 4; ks++) {
      bf16x8 v = *(const bf16x8*)&Qg[base + (size_t)qrow * 64 + ks * 16 + qh * 8];
#pragma unroll
      for (int j = 0; j < 8; j++) v[j] = (__bf16)((float)v[j] * cs);
      bq[ks] = v;
    }

    f32x16 ot[2] = {};                  // O^T acc: d-tiles {0..31},{32..63}
    float m_run = -1e30f, l_run = 0.0f;

    auto step = [&](auto diagc, const short* ksb, const short* vsb) {
      constexpr bool DIAG = decltype(diagc)::value;

      // ---- S^T = K * Q^T (K frags straight from LDS, conflict-free) ----
      f32x16 st[4] = {};
      __builtin_amdgcn_s_setprio(1);
#pragma unroll
      for (int mt = 0; mt < 4; mt++)
#pragma unroll
        for (int ks = 0; ks < 4; ks++) {
          bf16x8 ak = *(const bf16x8*)&ksb[(mt * 4 + ks) * 512 + laneoff];
          st[mt] = __builtin_amdgcn_mfma_f32_32x32x16_bf16(ak, bq[ks],
                                                           st[mt], 0, 0, 0);
        }
      __builtin_amdgcn_s_setprio(0);

      // ---- softmax (in-register; one shfl pair with lane^32) ----
      float tm[4];
#pragma unroll
      for (int mt = 0; mt < 4; mt++) {
        float t = -1e30f;
#pragma unroll
        for (int r = 0; r < 16; r++) {
          if (DIAG) {
            int krel = mt * 32 + (r & 3) + 8 * (r >> 2) + 4 * qh;
            if (krel > q_rel) st[mt][r] = -1e30f;
          }
          t = fmaxf(t, st[mt][r]);
        }
        tm[mt] = t;
      }
      float tmax = fmaxf(fmaxf(tm[0], tm[1]), fmaxf(tm[2], tm[3]));
      tmax = fmaxf(tmax, __shfl_xor(tmax, 32));
      // defer-max (T13): skip O-rescale while max growth bounded (P <= 2^8)
      if (!__all(tmax - m_run <= 8.0f)) {
        const float mnew = fmaxf(m_run, tmax);
        const float alpha = __builtin_amdgcn_exp2f(m_run - mnew);
        l_run *= alpha;
#pragma unroll
        for (int mt = 0; mt < 2; mt++)
#pragma unroll
          for (int r = 0; r < 16; r++) ot[mt][r] *= alpha;
        m_run = mnew;
      }
      float ps[4];
#pragma unroll
      for (int mt = 0; mt < 4; mt++) {
        float s = 0.0f;
#pragma unroll
        for (int r = 0; r < 16; r++) {
          float p = __builtin_amdgcn_exp2f(st[mt][r] - m_run);
          s += p;
          st[mt][r] = p;
        }
        ps[mt] = s;
      }
      float psum = (ps[0] + ps[1]) + (ps[2] + ps[3]);
      psum += __shfl_xor(psum, 32);
      l_run += psum;

      // ---- O^T += V^T * P^T (P^T built in-register via permlane32_swap) ----
      __builtin_amdgcn_s_setprio(1);
#pragma unroll
      for (int kb = 0; kb < 8; kb++) {
        const int mt = kb >> 1, rb = (kb & 1) * 8;
        unsigned x0 = pk2bf(st[mt][rb + 0], st[mt][rb + 1]);
        unsigned x1 = pk2bf(st[mt][rb + 2], st[mt][rb + 3]);
        unsigned y0 = pk2bf(st[mt][rb + 4], st[mt][rb + 5]);
        unsigned y1 = pk2bf(st[mt][rb + 6], st[mt][rb + 7]);
        asm("v_permlane32_swap_b32 %0, %1" : "+v"(x0), "+v"(y0));
        asm("v_permlane32_swap_b32 %0, %1" : "+v"(x1), "+v"(y1));
        uint4_t pw;
        pw[0] = x0; pw[1] = x1; pw[2] = y0; pw[3] = y1;
        bf16x8 pb = __builtin_bit_cast(bf16x8, pw);
#pragma unroll
        for (int mtv = 0; mtv < 2; mtv++) {
          bf16x8 av = *(const bf16x8*)&vsb[(kb * 2 + mtv) * 512 + laneoff];
          ot[mtv] = __builtin_amdgcn_mfma_f32_32x32x16_bf16(av, pb,
                                                            ot[mtv], 0, 0, 0);
        }
      }
      __builtin_amdgcn_s_setprio(0);
    };

    __syncthreads();                    // buffers free (prior half done)
    stage(cur, 0);
    for (int kt = 0; kt <= qt; kt++) {
      __syncthreads();                  // vmcnt(0) drain => buf[cur] ready
      if (kt < qt) stage(cur ^ 1, kt + 1);   // prefetch overlaps compute
      if (kt == qt)
        step(std::integral_constant<bool, true>{}, Ks[cur], Vs[cur]);
      else
        step(std::integral_constant<bool, false>{}, Ks[cur], Vs[cur]);
      cur ^= 1;
    }

    // ---- epilogue: O[b, qrow, h*64+d] = O^T / l ----
    const float inv = 1.0f / l_run;
    const size_t obase = ((size_t)b * 2048 + qrow) * 1024 + h * 64 + qh * 4;
#pragma unroll
    for (int mt = 0; mt < 2; mt++)
#pragma unroll
      for (int rr = 0; rr < 4; rr++) {
        short4_t ov;
#pragma unroll
        for (int i = 0; i < 4; i++) ov[i] = f2bf(ot[mt][rr * 4 + i] * inv);
        *(short4_t*)&Og[obase + mt * 32 + rr * 8] = ov;
      }
  }
}

// ---------------- launch ----------------
extern "C" void kernel_launch(void* const* d_in, const int* in_sizes, int n_in,
                              void* d_out, int out_size, void* d_ws, size_t ws_size,
                              hipStream_t stream) {
  const float* x      = (const float*)d_in[0];   // [4,2048,1024]
  const float* w_qkv  = (const float*)d_in[1];   // [1024,3072]
  const float* w_proj = (const float*)d_in[2];   // [1024,1024]
  float* out = (float*)d_out;                    // [4,2048,1024]

  char* ws = (char*)d_ws;
  short* xb     = (short*)(ws);                    // 16 MB bf16 x; reused as O
  short* wqkvT  = (short*)(ws + 16777216);         // 6 MB
  short* wprojT = (short*)(ws + 23068672);         // 2 MB
  short* Qb     = (short*)(ws + 25165824);         // 16 MB  [B,H,T,D]
  short* Kb     = (short*)(ws + 41943040);         // 16 MB  [B,H,T,D]
  short* Vtb    = (short*)(ws + 58720256);         // 16 MB  [B,H,D,T]

  convert_bf16<<<8192, 256, 0, stream>>>(x, xb);
  {
    dim3 gq(96, 32); transpose_bf16<<<gq, 256, 0, stream>>>(w_qkv, wqkvT, 1024, 3072);
    dim3 gp(32, 32); transpose_bf16<<<gp, 256, 0, stream>>>(w_proj, wprojT, 1024, 1024);
  }
  {
    dim3 g(24, 64);  // N/128, M/128
    gemm_bt<1><<<g, 256, 0, stream>>>(xb, wqkvT, nullptr, Qb, Kb, Vtb, 8192, 3072, 1024);
  }
  {
    // grid: x = b*h (same bh -> same XCD under linear%8 round-robin),
    //       y = paired q-tiles (qt, 15-qt) -> uniform 17 k-iterations
    dim3 g(64, 8);
    attn_fwd<<<g, 256, 0, stream>>>(Qb, Kb, Vtb, xb /* O, reusing xb */);
  }
  {
    dim3 g(8, 64);
    gemm_bt<0><<<g, 256, 0, stream>>>(xb, wprojT, out, nullptr, nullptr, nullptr,
                                      8192, 1024, 1024);
  }
}